// Round 1
// baseline (1392.173 us; speedup 1.0000x reference)
//
#include <hip/hip_runtime.h>
#include <hip/hip_bf16.h>
#include <math.h>

// Problem constants (Conv-KNRM)
#define B_    128
#define Qn    30
#define Dn    200
#define En    300
#define Cn    128
#define Kk    11
// derived sizes
#define QN_STRIDE (B_*Qn*Cn)   // 491520  per-gram q output
#define DN_STRIDE (B_*Dn*Cn)   // 3276800 per-gram d output
#define W2T_SZ (2*Cn*En)       // 76800
#define W3T_SZ (3*Cn*En)       // 115200

__device__ __constant__ float MU_[11] =
    {1.0f, 0.9f, 0.7f, 0.5f, 0.3f, 0.1f, -0.1f, -0.3f, -0.5f, -0.7f, -0.9f};
// 1/(2*sigma^2): sigma = 0.001 for k=0, 0.1 otherwise
__device__ __constant__ float IS_[11] =
    {500000.0f, 50.0f, 50.0f, 50.0f, 50.0f, 50.0f, 50.0f, 50.0f, 50.0f, 50.0f, 50.0f};

__device__ __forceinline__ float dot4f(float4 a, float4 b) {
    return a.x*b.x + a.y*b.y + a.z*b.z + a.w*b.w;
}

// ---------------------------------------------------------------------------
// Prep: transpose conv_w2 [C][E][2] -> w2t [2][C][E], conv_w3 [C][E][3] -> w3t [3][C][E]
// so the conv kernel can do contiguous float4 loads along E.
// ---------------------------------------------------------------------------
__global__ void prep_w_kernel(const float* __restrict__ w2, const float* __restrict__ w3,
                              float* __restrict__ w2t, float* __restrict__ w3t) {
    int idx = blockIdx.x * 256 + threadIdx.x;
    if (idx < W2T_SZ) {
        int j = idx / (Cn*En);
        int r = idx - j*(Cn*En);
        int c = r / En;
        int e = r - c*En;
        w2t[idx] = w2[c*(En*2) + e*2 + j];
    }
    if (idx < W3T_SZ) {
        int j = idx / (Cn*En);
        int r = idx - j*(Cn*En);
        int c = r / En;
        int e = r - c*En;
        w3t[idx] = w3[c*(En*3) + e*3 + j];
    }
}

// ---------------------------------------------------------------------------
// Fused: embedding gather -> 3 convs (k=1,2,3, pad end) -> +bias -> relu ->
//        L2-normalize over C -> store normalized grams.
// Block: one (batch, 16-position tile). 256 threads = 128 channels x 2 halves.
// ---------------------------------------------------------------------------
__global__ __launch_bounds__(256) void conv_norm_kernel(
    const int* __restrict__ tokens, int L,
    const float* __restrict__ emb,
    const float* __restrict__ w1,    // [C][E]
    const float* __restrict__ w2t,   // [2][C][E]
    const float* __restrict__ w3t,   // [3][C][E]
    const float* __restrict__ b1, const float* __restrict__ b2, const float* __restrict__ b3,
    float* __restrict__ out1, float* __restrict__ out2, float* __restrict__ out3)
{
    __shared__ __align__(16) float xs[18][304];   // 16 + 2 pad rows, E padded
    __shared__ __align__(16) float ys[3][16][129];
    __shared__ float rn[3][16];
    __shared__ int toks[18];

    const int b   = blockIdx.y;
    const int l0  = blockIdx.x * 16;
    const int tid = threadIdx.x;

    if (tid < 18) {
        int l = l0 + tid;
        toks[tid] = (l < L) ? tokens[b*L + l] : -1;
    }
    __syncthreads();

    // gather embedding rows (zeros for padding / out-of-range)
    for (int idx = tid; idx < 18*En; idx += 256) {
        int r = idx / En;
        int e = idx - r*En;
        int t = toks[r];
        xs[r][e] = (t >= 0) ? emb[t*En + e] : 0.0f;
    }
    __syncthreads();

    const int c    = tid & 127;
    const int half = tid >> 7;
    const int p0   = half * 8;

    float a1[8], a2[8], a3[8];
    #pragma unroll
    for (int p = 0; p < 8; ++p) { a1[p] = 0.f; a2[p] = 0.f; a3[p] = 0.f; }

    const float* w1r  = w1  + c*En;
    const float* w2r0 = w2t + c*En;
    const float* w2r1 = w2t + Cn*En + c*En;
    const float* w3r0 = w3t + c*En;
    const float* w3r1 = w3t + Cn*En + c*En;
    const float* w3r2 = w3t + 2*Cn*En + c*En;

    for (int e = 0; e < En; e += 4) {
        float4 W1  = *(const float4*)(w1r  + e);
        float4 W2a = *(const float4*)(w2r0 + e);
        float4 W2b = *(const float4*)(w2r1 + e);
        float4 W3a = *(const float4*)(w3r0 + e);
        float4 W3b = *(const float4*)(w3r1 + e);
        float4 W3c = *(const float4*)(w3r2 + e);
        float4 xv[10];
        #pragma unroll
        for (int j = 0; j < 10; ++j) xv[j] = *(const float4*)(&xs[p0 + j][e]);
        #pragma unroll
        for (int p = 0; p < 8; ++p) {
            a1[p] += dot4f(W1, xv[p]);
            a2[p] += dot4f(W2a, xv[p]) + dot4f(W2b, xv[p+1]);
            a3[p] += dot4f(W3a, xv[p]) + dot4f(W3b, xv[p+1]) + dot4f(W3c, xv[p+2]);
        }
    }

    const float bias1 = b1[c], bias2 = b2[c], bias3 = b3[c];
    #pragma unroll
    for (int p = 0; p < 8; ++p) {
        ys[0][p0+p][c] = fmaxf(a1[p] + bias1, 0.0f);
        ys[1][p0+p][c] = fmaxf(a2[p] + bias2, 0.0f);
        ys[2][p0+p][c] = fmaxf(a3[p] + bias3, 0.0f);
    }
    __syncthreads();

    if (tid < 48) {
        int g = tid >> 4, p = tid & 15;
        float s = 0.0f;
        for (int i = 0; i < Cn; ++i) { float v = ys[g][p][i]; s += v*v; }
        rn[g][p] = 1.0f / (sqrtf(s) + 1e-13f);
    }
    __syncthreads();

    float* outs[3] = {out1, out2, out3};
    #pragma unroll
    for (int g = 0; g < 3; ++g) {
        #pragma unroll
        for (int p = 0; p < 8; ++p) {
            int l = l0 + p0 + p;
            if (l < L)
                outs[g][(b*L + l)*Cn + c] = ys[g][p0+p][c] * rn[g][p0+p];
        }
    }
}

// ---------------------------------------------------------------------------
// Pool: per (batch, qi*3+dj) combo: cos-sim GEMM (normalized inputs) ->
//       RBF soft-binning -> masked sum over d -> log -> masked sum over q.
// Block: 256 threads = 8 q-tiles(4) x 32 d-tiles(4); d processed in 2 chunks of 128.
// Dynamic LDS: qs[32][132] + ds[128][132] + pk[30][12] + qm[32] + dm[128]
// ---------------------------------------------------------------------------
__global__ __launch_bounds__(256) void pool_kernel(
    const float* __restrict__ qn_base,   // [3][B][Q][C]
    const float* __restrict__ dn_base,   // [3][B][D][C]
    const int* __restrict__ qtok, const int* __restrict__ dtok,
    float* __restrict__ feats)           // [B][9][11]
{
    extern __shared__ __align__(16) float smem[];
    float* qs  = smem;                 // 32*132 = 4224
    float* dsx = smem + 4224;          // 128*132 = 16896
    float* pk  = dsx + 16896;          // 30*12 = 360
    float* qm  = pk + 360;             // 32
    float* dm  = qm + 32;              // 128

    const int b     = blockIdx.y;
    const int combo = blockIdx.x;
    const int qi = combo / 3, dj = combo - 3*qi;
    const int tid = threadIdx.x;

    const float* qn = qn_base + qi*QN_STRIDE + b*Qn*Cn;
    const float* dn = dn_base + dj*DN_STRIDE + b*Dn*Cn;

    for (int idx = tid; idx < 32*Cn; idx += 256) {
        int q = idx >> 7, cc = idx & 127;
        qs[q*132 + cc] = (q < Qn) ? qn[q*Cn + cc] : 0.0f;
    }
    if (tid < 32) qm[tid] = (tid < Qn && qtok[b*Qn + tid] > 0) ? 1.0f : 0.0f;
    for (int idx = tid; idx < 360; idx += 256) pk[idx] = 0.0f;

    const int qt = tid >> 5, dt = tid & 31;
    const int q0 = qt * 4;
    const int d0 = dt * 4;

    for (int chunk = 0; chunk < 2; ++chunk) {
        __syncthreads();
        for (int idx = tid; idx < 128*Cn; idx += 256) {
            int dd = idx >> 7, cc = idx & 127;
            int d = chunk*128 + dd;
            dsx[dd*132 + cc] = (d < Dn) ? dn[d*Cn + cc] : 0.0f;
        }
        if (tid < 128) {
            int d = chunk*128 + tid;
            dm[tid] = (d < Dn && dtok[b*Dn + d] > 0) ? 1.0f : 0.0f;
        }
        __syncthreads();

        float acc[4][4];
        #pragma unroll
        for (int i = 0; i < 4; ++i)
            #pragma unroll
            for (int j = 0; j < 4; ++j) acc[i][j] = 0.0f;

        for (int ci = 0; ci < 32; ++ci) {
            int cc = 4 * ((ci + dt) & 31);   // dt-rotation spreads LDS banks
            float4 qv[4], dv[4];
            #pragma unroll
            for (int i = 0; i < 4; ++i) qv[i] = *(const float4*)(&qs[(q0+i)*132 + cc]);
            #pragma unroll
            for (int i = 0; i < 4; ++i) dv[i] = *(const float4*)(&dsx[(d0+i)*132 + cc]);
            #pragma unroll
            for (int i = 0; i < 4; ++i)
                #pragma unroll
                for (int j = 0; j < 4; ++j)
                    acc[i][j] += dot4f(qv[i], dv[j]);
        }

        #pragma unroll
        for (int i = 0; i < 4; ++i) {
            float qmv = qm[q0 + i];
            if (qmv == 0.0f) continue;
            float part[Kk];
            #pragma unroll
            for (int k = 0; k < Kk; ++k) part[k] = 0.0f;
            bool any = false;
            #pragma unroll
            for (int j = 0; j < 4; ++j) {
                float m = dm[d0 + j];
                if (m == 0.0f) continue;
                any = true;
                float cs = acc[i][j];
                #pragma unroll
                for (int k = 0; k < Kk; ++k) {
                    float t = cs - MU_[k];
                    part[k] += __expf(-t*t*IS_[k]);
                }
            }
            if (any) {
                #pragma unroll
                for (int k = 0; k < Kk; ++k)
                    atomicAdd(&pk[(q0+i)*12 + k], part[k]);
            }
        }
    }
    __syncthreads();

    // log(clip(.,1e-10))*0.01, masked by q_mask
    if (tid < Qn) {
        float qmv = qm[tid];
        for (int k = 0; k < Kk; ++k) {
            float s = pk[tid*12 + k];
            pk[tid*12 + k] = (qmv != 0.0f) ? 0.01f * logf(fmaxf(s, 1e-10f)) : 0.0f;
        }
    }
    __syncthreads();
    if (tid < Kk) {
        float s = 0.0f;
        for (int q = 0; q < Qn; ++q) s += pk[q*12 + tid];
        feats[(b*9 + combo)*Kk + tid] = s;
    }
}

// ---------------------------------------------------------------------------
// Final dense: out[b] = sum_f feats[b][f] * dense_w[f]
// ---------------------------------------------------------------------------
__global__ void final_kernel(const float* __restrict__ feats,
                             const float* __restrict__ dw,
                             float* __restrict__ out) {
    int b = threadIdx.x;
    if (b < B_) {
        float s = 0.0f;
        for (int f = 0; f < 9*Kk; ++f) s += feats[b*9*Kk + f] * dw[f];
        out[b] = s;
    }
}

extern "C" void kernel_launch(void* const* d_in, const int* in_sizes, int n_in,
                              void* d_out, int out_size, void* d_ws, size_t ws_size,
                              hipStream_t stream) {
    const int*   qtok = (const int*)d_in[0];
    const int*   dtok = (const int*)d_in[1];
    const float* emb  = (const float*)d_in[2];
    const float* w1   = (const float*)d_in[3];
    const float* w2   = (const float*)d_in[4];
    const float* w3   = (const float*)d_in[5];
    const float* b1   = (const float*)d_in[6];
    const float* b2   = (const float*)d_in[7];
    const float* b3   = (const float*)d_in[8];
    const float* dw   = (const float*)d_in[9];
    float* out = (float*)d_out;

    float* ws    = (float*)d_ws;
    float* qn    = ws;                       // 3 * 491520
    float* dn    = qn + 3*QN_STRIDE;         // 3 * 3276800
    float* w2t   = dn + 3*DN_STRIDE;         // 76800
    float* w3t   = w2t + W2T_SZ;             // 115200
    float* feats = w3t + W3T_SZ;             // 128*99

    prep_w_kernel<<<(W3T_SZ + 255)/256, 256, 0, stream>>>(w2, w3, w2t, w3t);

    conv_norm_kernel<<<dim3(2, B_), 256, 0, stream>>>(
        qtok, Qn, emb, w1, w2t, w3t, b1, b2, b3,
        qn, qn + QN_STRIDE, qn + 2*QN_STRIDE);

    conv_norm_kernel<<<dim3(13, B_), 256, 0, stream>>>(
        dtok, Dn, emb, w1, w2t, w3t, b1, b2, b3,
        dn, dn + DN_STRIDE, dn + 2*DN_STRIDE);

    const int pool_lds = (4224 + 16896 + 360 + 32 + 128) * 4;  // 86560 B
    hipFuncSetAttribute(reinterpret_cast<const void*>(pool_kernel),
                        hipFuncAttributeMaxDynamicSharedMemorySize, pool_lds);
    pool_kernel<<<dim3(9, B_), 256, pool_lds, stream>>>(qn, dn, qtok, dtok, feats);

    final_kernel<<<1, 128, 0, stream>>>(feats, dw, out);
}

// Round 2
// 252.746 us; speedup vs baseline: 5.5082x; 5.5082x over previous
//
#include <hip/hip_runtime.h>
#include <hip/hip_bf16.h>
#include <math.h>

#define B_   128
#define Qn   30
#define Dn   200
#define En   300
#define QP   32
#define DP   208

typedef __attribute__((ext_vector_type(8))) short short8;
typedef __attribute__((ext_vector_type(4))) float floatx4;
typedef unsigned int u32;
typedef unsigned short u16;

typedef const __attribute__((address_space(1))) unsigned int* gas_ptr;
typedef __attribute__((address_space(3))) unsigned int* las_ptr;

static __device__ __forceinline__ void gld_lds16(const void* g, void* l) {
    __builtin_amdgcn_global_load_lds((gas_ptr)g, (las_ptr)l, 16, 0, 0);
}

static __device__ __forceinline__ u16 f2b(float x) {   // fp32 -> bf16 RNE
    union { float f; u32 u; } v; v.f = x;
    u32 r = v.u + 0x7FFFu + ((v.u >> 16) & 1u);
    return (u16)(r >> 16);
}
static __device__ __forceinline__ float bits2f(u32 u) {
    union { u32 u; float f; } v; v.u = u; return v.f;
}

// ---------------------------------------------------------------------------
// Prep: weights -> bf16 Wt[6][128][320] (tapmats: w1 | w2j0 w2j1 | w3j0 w3j1 w3j2),
// K zero-padded 300->320.
// ---------------------------------------------------------------------------
__global__ void prep_w_kernel(const float* __restrict__ w1, const float* __restrict__ w2,
                              const float* __restrict__ w3, u16* __restrict__ Wt) {
    int idx = blockIdx.x * 256 + threadIdx.x;           // < 6*128*320 = 245760
    if (idx >= 6*128*320) return;
    int t = idx / 40960;
    int rem = idx - t * 40960;
    int c = rem / 320;
    int e = rem - c * 320;
    float v = 0.f;
    if (e < 300) {
        if (t == 0)       v = w1[c*300 + e];
        else if (t <= 2)  v = w2[(c*300 + e)*2 + (t - 1)];
        else              v = w3[(c*300 + e)*3 + (t - 3)];
    }
    Wt[idx] = f2b(v);
}

// ---------------------------------------------------------------------------
// Fused conv: gather emb -> bf16 A-tile (32 pos x 320 K) in LDS; K-loop stages
// 48KB weight slices via global_load_lds; MFMA 16x16x32 bf16 with tap-shifted
// A-frags; epilogue: +bias, relu, bf16-round, store raw bf16 + 1/(||x_bf16||+1e-13).
// Block = (chunk, b). chunk 0 = query (30 pos), chunks 1..7 = doc (30 pos each).
// LDS: A [32][328] u16 = 20992 B | B [48 groups][1024 B] = 49152 B (reused as outs).
// ---------------------------------------------------------------------------
__global__ __launch_bounds__(256, 2) void conv_kernel(
    const int* __restrict__ qtok, const int* __restrict__ dtok,
    const float* __restrict__ emb, const u16* __restrict__ Wt,
    const float* __restrict__ b1, const float* __restrict__ b2, const float* __restrict__ b3,
    u16* __restrict__ qb, u16* __restrict__ db,
    float* __restrict__ invnq, float* __restrict__ invnd)
{
    extern __shared__ char smem[];
    char* Asb = smem;                 // [32][328] u16
    char* Bsb = smem + 20992;         // [48][1024B]; epilogue overlay: outs [3][32][136] u16
    __shared__ int toks[32];

    const int tid = threadIdx.x;
    const int b   = blockIdx.y;
    const int cx  = blockIdx.x;
    const bool isq = (cx == 0);
    const int l0 = isq ? 0 : (cx - 1) * 30;
    const int L  = isq ? Qn : Dn;
    const int LP = isq ? QP : DP;
    const int* tok = isq ? qtok : dtok;
    u16* outg   = isq ? qb : db;
    float* invg = isq ? invnq : invnd;

    if (tid < 32) {
        int l = l0 + tid;
        toks[tid] = (l < L) ? tok[b*L + l] : -1;
    }
    __syncthreads();

    // stage A: 32 rows x 300 cols fp32 -> bf16, cols 300..327 zero
    for (int f = tid; f < 32*75; f += 256) {
        int row = f / 75, e4 = f - row*75;
        int t = toks[row];
        float4 v = make_float4(0.f, 0.f, 0.f, 0.f);
        if (t >= 0) v = *(const float4*)(emb + t*En + e4*4);
        u16* p = (u16*)Asb + row*328 + e4*4;
        p[0] = f2b(v.x); p[1] = f2b(v.y); p[2] = f2b(v.z); p[3] = f2b(v.w);
    }
    for (int f = tid; f < 32*28; f += 256) {
        int row = f / 28, cc = f - row*28;
        ((u16*)Asb)[row*328 + 300 + cc] = 0;
    }

    const int wv = tid >> 6, lane = tid & 63;
    const int l15 = lane & 15, qd4 = lane >> 4;
    const int stage_off = l15*640 + qd4*16;     // bytes within Wt row-group
    const int afl = l15*656 + qd4*16;           // A frag lane offset (bytes)
    const int bfl = lane*16;                    // B frag lane offset (bytes, contiguous 1KB group)

    floatx4 acc[3][2][2];
    #pragma unroll
    for (int g = 0; g < 3; ++g)
        #pragma unroll
        for (int mt = 0; mt < 2; ++mt)
            #pragma unroll
            for (int nt = 0; nt < 2; ++nt)
                acc[g][mt][nt] = (floatx4){0.f, 0.f, 0.f, 0.f};

    static const int TG[6] = {0,1,1,2,2,2};
    static const int TJ[6] = {0,0,1,0,1,2};

    for (int ks = 0; ks < 10; ++ks) {
        __syncthreads();    // B buffer free (and A staged, first iter)
        {
            const char* gp = (const char*)Wt + ks*64 + stage_off + wv*12*10240;
            char* lp = Bsb + wv*12*1024;
            #pragma unroll
            for (int i = 0; i < 12; ++i)
                gld_lds16(gp + i*10240, lp + i*1024);
        }
        __syncthreads();    // DMA drained (vmcnt(0) before barrier)

        short8 af[2][3];
        #pragma unroll
        for (int mt = 0; mt < 2; ++mt)
            #pragma unroll
            for (int j = 0; j < 3; ++j)
                af[mt][j] = *(const short8*)(Asb + (mt*16 + j)*656 + ks*64 + afl);

        #pragma unroll
        for (int t = 0; t < 6; ++t) {
            #pragma unroll
            for (int nt = 0; nt < 2; ++nt) {
                short8 bf = *(const short8*)(Bsb + (t*8 + wv*2 + nt)*1024 + bfl);
                #pragma unroll
                for (int mt = 0; mt < 2; ++mt)
                    acc[TG[t]][mt][nt] = __builtin_amdgcn_mfma_f32_16x16x32_bf16(
                        af[mt][TJ[t]], bf, acc[TG[t]][mt][nt], 0, 0, 0);
            }
        }
    }
    __syncthreads();        // frag reads done; Bs can be overlaid

    // epilogue: bias + relu + bf16 into LDS outs [3][32][136]
    u16* outs = (u16*)Bsb;
    float bias[3][2];
    #pragma unroll
    for (int nt = 0; nt < 2; ++nt) {
        int c = wv*32 + nt*16 + l15;
        bias[0][nt] = b1[c]; bias[1][nt] = b2[c]; bias[2][nt] = b3[c];
    }
    #pragma unroll
    for (int g = 0; g < 3; ++g)
        #pragma unroll
        for (int mt = 0; mt < 2; ++mt)
            #pragma unroll
            for (int nt = 0; nt < 2; ++nt) {
                int c = wv*32 + nt*16 + l15;
                #pragma unroll
                for (int i = 0; i < 4; ++i) {
                    int m = mt*16 + qd4*4 + i;
                    float v = fmaxf(acc[g][mt][nt][i] + bias[g][nt], 0.f);
                    outs[(g*32 + m)*136 + c] = f2b(v);
                }
            }
    __syncthreads();

    const int countW = isq ? 32 : ((30 < DP - l0) ? 30 : (DP - l0));

    // inverse norms from the bf16-rounded values (consistent q/d path => exact-match cos == 1)
    if (tid < 96) {
        int g = tid >> 5, m = tid & 31;
        const char* rowp = Bsb + (g*32 + m)*272;
        float s = 0.f;
        #pragma unroll
        for (int t16 = 0; t16 < 16; ++t16) {
            uint4 u = *(const uint4*)(rowp + t16*16);
            float x;
            x = bits2f(u.x << 16);          s += x*x;
            x = bits2f(u.x & 0xffff0000u);  s += x*x;
            x = bits2f(u.y << 16);          s += x*x;
            x = bits2f(u.y & 0xffff0000u);  s += x*x;
            x = bits2f(u.z << 16);          s += x*x;
            x = bits2f(u.z & 0xffff0000u);  s += x*x;
            x = bits2f(u.w << 16);          s += x*x;
            x = bits2f(u.w & 0xffff0000u);  s += x*x;
        }
        float inv = 1.f / (sqrtf(s) + 1e-13f);
        if (m < countW) {
            int l = l0 + m;
            invg[(g*B_ + b)*LP + l] = (l < L) ? inv : 0.f;
        }
    }

    // copy outs -> global (zeros for padded positions l >= L)
    const int tot = 3 * countW * 16;
    for (int idx = tid; idx < tot; idx += 256) {
        int g = idx / (countW*16);
        int rem = idx - g*(countW*16);
        int m = rem >> 4, ch = rem & 15;
        int l = l0 + m;
        uint4 v = make_uint4(0u, 0u, 0u, 0u);
        if (l < L) v = *(const uint4*)(Bsb + (g*32 + m)*272 + ch*16);
        *(uint4*)(outg + ((g*B_ + b)*LP + l)*128 + ch*8) = v;
    }
}

// ---------------------------------------------------------------------------
// Pool: block = (dj, b). MFMA cos GEMM: A = doc rows (M), B = all 3 q-grams
// stacked (N = 96). C-layout col = q  => per-lane RBF accumulation in regs.
// Masks folded into inv-norms: q-masked -> invq=0 (cos=0), d-masked -> invd<0
// (cos<=0); valid cos > 0 always (relu vectors). cos<=0 mapped to 2.0 where
// every RBF kernel underflows to exactly 0.
// ---------------------------------------------------------------------------
__global__ __launch_bounds__(256, 2) void pool_kernel(
    const u16* __restrict__ qb, const u16* __restrict__ db,
    const float* __restrict__ invnq, const float* __restrict__ invnd,
    const int* __restrict__ qtok, const int* __restrict__ dtok,
    float* __restrict__ feats)
{
    extern __shared__ char smem[];
    char* qsb  = smem;                         // [96][136] u16 = 26112
    char* dsb  = smem + 26112;                 // [112][136] u16 = 30464
    float* pk   = (float*)(smem + 56576);      // [96][12] = 4608 B
    float* invq = (float*)(smem + 61184);      // [96]  (qmask folded: 0 if masked)
    float* invd = (float*)(smem + 61568);      // [208] (dmask folded: negative if masked)
    float* qm   = (float*)(smem + 62400);      // [32]

    const int tid = threadIdx.x;
    const int b = blockIdx.y, dj = blockIdx.x;
    const int wv = tid >> 6, lane = tid & 63;
    const int l15 = lane & 15, qd4 = lane >> 4;

    // stage q grams: 96 rows x 128 bf16
    {
        int ch = tid & 15, r0 = tid >> 4;
        #pragma unroll
        for (int it = 0; it < 6; ++it) {
            int r = r0 + it*16;
            int qi = r >> 5, qr = r & 31;
            uint4 v = *(const uint4*)(qb + ((qi*B_ + b)*QP + qr)*128 + ch*8);
            *(uint4*)(qsb + r*272 + ch*16) = v;
        }
    }
    if (tid < 96) {
        int qr = tid & 31;
        float v = invnq[((tid >> 5)*B_ + b)*QP + qr];
        bool ok = (qr < Qn) && (qtok[b*Qn + qr] > 0);
        invq[tid] = ok ? v : 0.f;
    }
    if (tid < DP) {
        float v = invnd[(dj*B_ + b)*DP + tid];
        bool ok = (tid < Dn) && (dtok[b*Dn + tid] > 0);
        invd[tid] = ok ? v : -v - 1.f;   // strictly negative when masked
    }
    if (tid < 32) qm[tid] = (tid < Qn && qtok[b*Qn + tid] > 0) ? 1.f : 0.f;
    for (int i = tid; i < 96*12; i += 256) pk[i] = 0.f;
    __syncthreads();

    // q fragments resident in registers: 6 q-tiles x 4 K-steps
    short8 qf[6][4];
    #pragma unroll
    for (int qt = 0; qt < 6; ++qt)
        #pragma unroll
        for (int ks = 0; ks < 4; ++ks)
            qf[qt][ks] = *(const short8*)(qsb + (qt*16 + l15)*272 + ks*64 + qd4*16);
    float vq[6];
    #pragma unroll
    for (int qt = 0; qt < 6; ++qt) vq[qt] = invq[qt*16 + l15];

    float pkl[6][11];
    #pragma unroll
    for (int qt = 0; qt < 6; ++qt)
        #pragma unroll
        for (int k = 0; k < 11; ++k) pkl[qt][k] = 0.f;

    const float MUc[11]  = {1.0f,0.9f,0.7f,0.5f,0.3f,0.1f,-0.1f,-0.3f,-0.5f,-0.7f,-0.9f};
    const float NISc[11] = {-500000.0f,-50.f,-50.f,-50.f,-50.f,-50.f,-50.f,-50.f,-50.f,-50.f,-50.f};

    for (int c2 = 0; c2 < 2; ++c2) {
        const int R0 = c2 * 112;
        const int RN = c2 ? 96 : 112;
        __syncthreads();
        for (int idx = tid; idx < RN*16; idx += 256) {
            int r = idx >> 4, ch = idx & 15;
            uint4 v = *(const uint4*)(db + ((dj*B_ + b)*DP + R0 + r)*128 + ch*8);
            *(uint4*)(dsb + r*272 + ch*16) = v;
        }
        __syncthreads();

        for (int t = (c2 ? 7 : 0) + wv; t < (c2 ? 13 : 7); t += 4) {
            int lrow = t*16 - R0 + l15;
            short8 af[4];
            #pragma unroll
            for (int ks = 0; ks < 4; ++ks)
                af[ks] = *(const short8*)(dsb + lrow*272 + ks*64 + qd4*16);

            floatx4 acc6[6];
            #pragma unroll
            for (int qt = 0; qt < 6; ++qt) acc6[qt] = (floatx4){0.f, 0.f, 0.f, 0.f};
            #pragma unroll
            for (int ks = 0; ks < 4; ++ks)
                #pragma unroll
                for (int qt = 0; qt < 6; ++qt)
                    acc6[qt] = __builtin_amdgcn_mfma_f32_16x16x32_bf16(af[ks], qf[qt][ks], acc6[qt], 0, 0, 0);

            int dg = t*16 + qd4*4;
            floatx4 ivd = *(const floatx4*)(invd + dg);
            #pragma unroll
            for (int qt = 0; qt < 6; ++qt) {
                #pragma unroll
                for (int i = 0; i < 4; ++i) {
                    float cs = acc6[qt][i] * vq[qt] * ivd[i];
                    cs = (cs > 0.f) ? cs : 2.0f;     // masked/invalid -> all kernels underflow to 0
                    #pragma unroll
                    for (int k = 0; k < 11; ++k) {
                        float d = cs - MUc[k];
                        pkl[qt][k] += __expf(d*d*NISc[k]);
                    }
                }
            }
        }
    }

    // merge per-lane partials (4 lanes/wave x 4 waves share each q)
    #pragma unroll
    for (int qt = 0; qt < 6; ++qt) {
        int q = qt*16 + l15;
        #pragma unroll
        for (int k = 0; k < 11; ++k)
            atomicAdd(&pk[q*12 + k], pkl[qt][k]);
    }
    __syncthreads();

    if (tid < 33) {
        int qi = tid / 11, k = tid - qi*11;
        float s = 0.f;
        for (int q = 0; q < 32; ++q) {
            float v = pk[(qi*32 + q)*12 + k];
            s += qm[q] * 0.01f * logf(fmaxf(v, 1e-10f));
        }
        feats[(b*9 + qi*3 + dj)*11 + k] = s;
    }
}

// ---------------------------------------------------------------------------
__global__ void final_kernel(const float* __restrict__ feats,
                             const float* __restrict__ dw,
                             float* __restrict__ out) {
    int b = threadIdx.x;
    if (b < B_) {
        float s = 0.f;
        for (int f = 0; f < 99; ++f) s += feats[b*99 + f] * dw[f];
        out[b] = s;
    }
}

extern "C" void kernel_launch(void* const* d_in, const int* in_sizes, int n_in,
                              void* d_out, int out_size, void* d_ws, size_t ws_size,
                              hipStream_t stream) {
    const int*   qtok = (const int*)d_in[0];
    const int*   dtok = (const int*)d_in[1];
    const float* emb  = (const float*)d_in[2];
    const float* w1   = (const float*)d_in[3];
    const float* w2   = (const float*)d_in[4];
    const float* w3   = (const float*)d_in[5];
    const float* b1   = (const float*)d_in[6];
    const float* b2   = (const float*)d_in[7];
    const float* b3   = (const float*)d_in[8];
    const float* dw   = (const float*)d_in[9];
    float* out = (float*)d_out;

    char* w = (char*)d_ws;
    u16*   Wt    = (u16*)w;                      // 491520 B
    u16*   qb    = (u16*)(w + 491520);           // 3*128*32*128*2  = 3145728 B
    u16*   db    = (u16*)(w + 3637248);          // 3*128*208*128*2 = 20447232 B
    float* invnq = (float*)(w + 24084480);       // 49152 B
    float* invnd = (float*)(w + 24133632);       // 319488 B
    float* feats = (float*)(w + 24453120);       // 50688 B

    prep_w_kernel<<<960, 256, 0, stream>>>(w1, w2, w3, Wt);

    const int conv_lds = 20992 + 49152;          // 70144 B
    hipFuncSetAttribute(reinterpret_cast<const void*>(conv_kernel),
                        hipFuncAttributeMaxDynamicSharedMemorySize, conv_lds);
    conv_kernel<<<dim3(8, B_), 256, conv_lds, stream>>>(
        qtok, dtok, emb, Wt, b1, b2, b3, qb, db, invnq, invnd);

    const int pool_lds = 63360;
    pool_kernel<<<dim3(3, B_), 256, pool_lds, stream>>>(
        qb, db, invnq, invnd, qtok, dtok, feats);

    final_kernel<<<1, 128, 0, stream>>>(feats, dw, out);
}

// Round 4
// 249.877 us; speedup vs baseline: 5.5714x; 1.0115x over previous
//
#include <hip/hip_runtime.h>
#include <hip/hip_bf16.h>
#include <math.h>

#define B_   128
#define Qn   30
#define Dn   200
#define En   300

typedef __attribute__((ext_vector_type(8))) short short8;
typedef __attribute__((ext_vector_type(4))) float floatx4;
typedef unsigned int u32;
typedef unsigned short u16;

typedef const __attribute__((address_space(1))) unsigned int* gas_ptr;
typedef __attribute__((address_space(3))) unsigned int* las_ptr;

static __device__ __forceinline__ void gld_lds16(const void* g, void* l) {
    __builtin_amdgcn_global_load_lds((gas_ptr)g, (las_ptr)l, 16, 0, 0);
}

static __device__ __forceinline__ u16 f2b(float x) {   // fp32 -> bf16 RNE
    union { float f; u32 u; } v; v.f = x;
    u32 r = v.u + 0x7FFFu + ((v.u >> 16) & 1u);
    return (u16)(r >> 16);
}
static __device__ __forceinline__ float bits2f(u32 u) {
    union { u32 u2; float f; } v; v.u2 = u; return v.f;
}

// ---------------------------------------------------------------------------
// Prep: weights -> bf16 Wt[6 tapmats][128 ch][320 K] (K zero-padded 300->320).
// tapmats: t0=w1; t1,2=w2 taps 0,1; t3,4,5=w3 taps 0,1,2.
// ---------------------------------------------------------------------------
__global__ void prep_w_kernel(const float* __restrict__ w1, const float* __restrict__ w2,
                              const float* __restrict__ w3, u16* __restrict__ Wt) {
    int idx = blockIdx.x * 256 + threadIdx.x;           // < 6*128*320 = 245760
    if (idx >= 6*128*320) return;
    int t = idx / 40960;
    int rem = idx - t * 40960;
    int c = rem / 320;
    int e = rem - c * 320;
    float v = 0.f;
    if (e < 300) {
        if (t == 0)       v = w1[c*300 + e];
        else if (t <= 2)  v = w2[(c*300 + e)*2 + (t - 1)];
        else              v = w3[(c*300 + e)*3 + (t - 3)];
    }
    Wt[idx] = f2b(v);
}

// ---------------------------------------------------------------------------
// Conv: one block = 128 positions of one batch item. grid (2, B).
//   tile0: d outputs 0..125   (A rows = d tokens 0..127)
//   tile1: d outputs 126..199 (A local 0..79 = d tokens 126..205, zero-pad >=200)
//          q outputs 0..29    (A local 80..111 = q tokens 0..31, zero-pad >=30)
//          A local 112..127 = zeros
// K-loop: 20 half-slices (K=32 x n-half 64ch x 6 taps = 24 KB), double-buffered
// via global_load_lds issued BEFORE the MFMA of the current slice.
// LDS: A [128][328]u16 = 83968 | B0 24576 | B1 24576  (= 133120 dynamic)
// Epilogue overlays Gs[128][136]u16 on B0/B1.
// ---------------------------------------------------------------------------
__global__ __launch_bounds__(256, 1) void conv_kernel(
    const int* __restrict__ qtok, const int* __restrict__ dtok,
    const float* __restrict__ emb, const u16* __restrict__ Wt,
    const float* __restrict__ b1, const float* __restrict__ b2, const float* __restrict__ b3,
    u16* __restrict__ qg, u16* __restrict__ dg,
    float* __restrict__ invnq, float* __restrict__ invnd)
{
    extern __shared__ char smem[];
    char* As = smem;                       // [128][328] u16
    char* Bb0 = smem + 83968;              // 24576
    char* Bb1 = smem + 108544;             // 24576
    __shared__ int toks[128];

    const int tid = threadIdx.x;
    const int b = blockIdx.y;
    const int tile = blockIdx.x;

    const int wv = tid >> 6, lane = tid & 63;
    const int l15 = lane & 15, qd4 = lane >> 4;
    const int lrow = lane >> 2, lchk = lane & 3;

    // per-lane global offsets for the 6 DMA instructions of this wave (h=0, ks=0)
    u32 goff[6];
    #pragma unroll
    for (int i = 0; i < 6; ++i) {
        int lr = (wv*6 + i)*16 + lrow;                 // 0..383 within half-slice
        goff[i] = (u32)((((lr >> 6)*128 + (lr & 63))*640) + lchk*16);
    }
    // issue slice 0 (ks=0, h=0) immediately
    {
        const char* base = (const char*)Wt;
        #pragma unroll
        for (int i = 0; i < 6; ++i)
            gld_lds16(base + goff[i], Bb0 + (wv*6 + i)*1024);
    }

    // token map
    if (tid < 128) {
        int tok;
        if (tile == 0) tok = dtok[b*Dn + tid];
        else {
            if (tid < 80)       { int l = 126 + tid; tok = (l < Dn) ? dtok[b*Dn + l] : -1; }
            else if (tid < 112) { int l = tid - 80;  tok = (l < Qn) ? qtok[b*Qn + l] : -1; }
            else tok = -1;
        }
        toks[tid] = tok;
    }
    __syncthreads();

    // gather embeddings -> bf16 A tile
    for (int f = tid; f < 128*75; f += 256) {
        int row = f / 75, e4 = f - row*75;
        int t = toks[row];
        float4 v = make_float4(0.f, 0.f, 0.f, 0.f);
        if (t >= 0) v = *(const float4*)(emb + t*En + e4*4);
        u16* p = (u16*)(As + row*656 + e4*8);
        p[0] = f2b(v.x); p[1] = f2b(v.y); p[2] = f2b(v.z); p[3] = f2b(v.w);
    }
    for (int f = tid; f < 128*14; f += 256) {          // zero K cols 300..327
        int row = f / 14, cc = f - row*14;
        *(u32*)(As + row*656 + 600 + cc*4) = 0u;
    }

    // biases (per n-tile channel of this lane)
    float bias[3][8];
    #pragma unroll
    for (int nt = 0; nt < 8; ++nt) {
        int c = nt*16 + l15;
        bias[0][nt] = b1[c]; bias[1][nt] = b2[c]; bias[2][nt] = b3[c];
    }

    floatx4 acc[3][2][8];
    #pragma unroll
    for (int g = 0; g < 3; ++g)
        #pragma unroll
        for (int mt = 0; mt < 2; ++mt)
            #pragma unroll
            for (int nt = 0; nt < 8; ++nt)
                acc[g][mt][nt] = (floatx4){0.f, 0.f, 0.f, 0.f};

    static const int TG[6] = {0,1,1,2,2,2};
    static const int TJ[6] = {0,0,1,0,1,2};

    short8 af[2][3];
    for (int s = 0; s < 20; ++s) {
        const int ks = s >> 1, h = s & 1;
        __syncthreads();                               // slice s drained & visible
        if (s < 19) {                                  // prefetch slice s+1 (overlaps MFMA)
            const int s1 = s + 1;
            const char* base = (const char*)Wt + (s1 >> 1)*64 + (s1 & 1)*40960;
            char* lb = (s1 & 1) ? Bb1 : Bb0;
            #pragma unroll
            for (int i = 0; i < 6; ++i)
                gld_lds16(base + goff[i], lb + (wv*6 + i)*1024);
        }
        if (h == 0) {
            #pragma unroll
            for (int mt = 0; mt < 2; ++mt)
                #pragma unroll
                for (int j = 0; j < 3; ++j)
                    af[mt][j] = *(const short8*)(As + (wv*32 + mt*16 + j + l15)*656 + ks*64 + qd4*16);
        }
        const char* Bc = (s & 1) ? Bb1 : Bb0;
        #pragma unroll
        for (int t = 0; t < 6; ++t) {
            #pragma unroll
            for (int nh = 0; nh < 4; ++nh) {
                short8 bf = *(const short8*)(Bc + (t*64 + nh*16 + l15)*64 + qd4*16);
                const int nt = h*4 + nh;
                #pragma unroll
                for (int mt = 0; mt < 2; ++mt)
                    acc[TG[t]][mt][nt] = __builtin_amdgcn_mfma_f32_16x16x32_bf16(
                        af[mt][TJ[t]], bf, acc[TG[t]][mt][nt], 0, 0, 0);
            }
        }
    }

    // epilogue: per gram: bias+relu+bf16 -> Gs -> norms + copy out
    u16* Gs = (u16*)Bb0;                               // [128][136]
    for (int g = 0; g < 3; ++g) {
        __syncthreads();                               // Gs free
        #pragma unroll
        for (int mt = 0; mt < 2; ++mt)
            #pragma unroll
            for (int nt = 0; nt < 8; ++nt) {
                int c = nt*16 + l15;
                #pragma unroll
                for (int i = 0; i < 4; ++i) {
                    int m = wv*32 + mt*16 + qd4*4 + i;
                    Gs[m*136 + c] = f2b(fmaxf(acc[g][mt][nt][i] + bias[g][nt], 0.f));
                }
            }
        __syncthreads();
        if (tid < 128) {                               // inverse norms (from bf16 values)
            const char* rp = (const char*)Gs + tid*272;
            float ssum = 0.f;
            #pragma unroll
            for (int t16 = 0; t16 < 16; ++t16) {
                uint4 u = *(const uint4*)(rp + t16*16);
                float x;
                x = bits2f(u.x << 16); ssum += x*x;  x = bits2f(u.x & 0xffff0000u); ssum += x*x;
                x = bits2f(u.y << 16); ssum += x*x;  x = bits2f(u.y & 0xffff0000u); ssum += x*x;
                x = bits2f(u.z << 16); ssum += x*x;  x = bits2f(u.z & 0xffff0000u); ssum += x*x;
                x = bits2f(u.w << 16); ssum += x*x;  x = bits2f(u.w & 0xffff0000u); ssum += x*x;
            }
            float inv = 1.f / (sqrtf(ssum) + 1e-13f);
            if (tile == 0) {
                if (tid < 126) invnd[(g*B_ + b)*208 + tid] = inv;
            } else {
                if (tid < 80)       invnd[(g*B_ + b)*208 + 126 + tid] = inv;
                else if (tid < 112) invnq[(g*B_ + b)*32 + (tid - 80)] = inv;
            }
        }
        {
            int ch = tid & 15, r0 = tid >> 4;
            #pragma unroll
            for (int p = 0; p < 8; ++p) {
                int r = p*16 + r0;
                uint4 v = *(const uint4*)((const char*)Gs + r*272 + ch*16);
                if (tile == 0) {
                    if (r < 126) *(uint4*)(dg + ((g*B_ + b)*208 + r)*128 + ch*8) = v;
                } else {
                    if (r < 80)       *(uint4*)(dg + ((g*B_ + b)*208 + 126 + r)*128 + ch*8) = v;
                    else if (r < 112) *(uint4*)(qg + ((g*B_ + b)*32 + (r - 80))*128 + ch*8) = v;
                }
            }
        }
    }
}

// ---------------------------------------------------------------------------
// Pool: block = (dj*2+chunk, b); grid (6, B). d-chunk (112 or 96 rows) in LDS,
// q-frags straight from L2, qi-loop keeps registers small. Per-chunk partial
// per-(q,k) sums -> pkg; merged + logged in final_kernel.
// FIX vs R3: zero-stage d rows with global position >= Dn (rows 206/207 of dg
// are never written by conv; 0xAA poison is negative bf16 and escaped the
// cs<=0 -> 2.0 masking remap).
// ---------------------------------------------------------------------------
__global__ __launch_bounds__(256, 3) void pool_kernel(
    const u16* __restrict__ qg, const u16* __restrict__ dg,
    const float* __restrict__ invnq, const float* __restrict__ invnd,
    const int* __restrict__ qtok, const int* __restrict__ dtok,
    float* __restrict__ pkg)
{
    __shared__ __align__(16) u16 dsb[112*136];
    __shared__ float pk[96*12];
    __shared__ float invq[96];
    __shared__ __align__(16) float invd[112];

    const int tid = threadIdx.x;
    const int b = blockIdx.y;
    const int dj = blockIdx.x >> 1, chunk = blockIdx.x & 1;
    const int base_r = chunk * 112;
    const int RN = chunk ? 96 : 112;
    const int NT = chunk ? 6 : 7;

    const int wv = tid >> 6, lane = tid & 63;
    const int l15 = lane & 15, qd4 = lane >> 4;

    for (int idx = tid; idx < RN*16; idx += 256) {
        int r = idx >> 4, ch = idx & 15;
        int gr = base_r + r;
        uint4 v = make_uint4(0u, 0u, 0u, 0u);
        if (gr < Dn) v = *(const uint4*)(dg + ((dj*B_ + b)*208 + gr)*128 + ch*8);
        *(uint4*)((char*)dsb + r*272 + ch*16) = v;
    }
    if (tid < RN) {
        int gr = base_r + tid;
        float v = invnd[(dj*B_ + b)*208 + gr];
        bool ok = (gr < Dn) && (dtok[b*Dn + gr] > 0);
        invd[tid] = ok ? v : (-fabsf(v) - 1.0f);       // strictly negative if masked
    }
    if (tid < 96) {
        int qi = tid >> 5, qr = tid & 31;
        float v = invnq[(qi*B_ + b)*32 + qr];
        bool ok = (qr < Qn) && (qtok[b*Qn + qr] > 0);
        invq[tid] = ok ? v : 0.f;
    }
    for (int i = tid; i < 96*12; i += 256) pk[i] = 0.f;
    __syncthreads();

    const float MUc[11]  = {1.0f,0.9f,0.7f,0.5f,0.3f,0.1f,-0.1f,-0.3f,-0.5f,-0.7f,-0.9f};
    const float NISc[11] = {-500000.f,-50.f,-50.f,-50.f,-50.f,-50.f,-50.f,-50.f,-50.f,-50.f,-50.f};

    for (int qi = 0; qi < 3; ++qi) {
        short8 qf[2][4];
        float vq[2];
        #pragma unroll
        for (int qt = 0; qt < 2; ++qt) {
            vq[qt] = invq[qi*32 + qt*16 + l15];
            #pragma unroll
            for (int ks = 0; ks < 4; ++ks)
                qf[qt][ks] = *(const short8*)(qg + ((qi*B_ + b)*32 + qt*16 + l15)*128 + ks*32 + qd4*8);
        }
        float pkl[2][11];
        #pragma unroll
        for (int qt = 0; qt < 2; ++qt)
            #pragma unroll
            for (int k = 0; k < 11; ++k) pkl[qt][k] = 0.f;

        for (int t = wv; t < NT; t += 4) {
            short8 af[4];
            #pragma unroll
            for (int ks = 0; ks < 4; ++ks)
                af[ks] = *(const short8*)((const char*)dsb + (t*16 + l15)*272 + ks*64 + qd4*16);
            floatx4 acc[2];
            acc[0] = (floatx4){0.f,0.f,0.f,0.f};
            acc[1] = (floatx4){0.f,0.f,0.f,0.f};
            #pragma unroll
            for (int ks = 0; ks < 4; ++ks)
                #pragma unroll
                for (int qt = 0; qt < 2; ++qt)
                    acc[qt] = __builtin_amdgcn_mfma_f32_16x16x32_bf16(af[ks], qf[qt][ks], acc[qt], 0, 0, 0);
            floatx4 iv4 = *(const floatx4*)(invd + t*16 + qd4*4);
            #pragma unroll
            for (int qt = 0; qt < 2; ++qt)
                #pragma unroll
                for (int i = 0; i < 4; ++i) {
                    float cs = acc[qt][i] * vq[qt] * iv4[i];
                    cs = (cs > 0.f) ? cs : 2.0f;       // masked/zero -> all kernels underflow to 0
                    #pragma unroll
                    for (int k = 0; k < 11; ++k) {
                        float d = cs - MUc[k];
                        pkl[qt][k] += __expf(d*d*NISc[k]);
                    }
                }
        }
        #pragma unroll
        for (int qt = 0; qt < 2; ++qt)
            #pragma unroll
            for (int k = 0; k < 11; ++k) {
                float v = pkl[qt][k];
                v += __shfl_xor(v, 16);
                v += __shfl_xor(v, 32);
                if (qd4 == 0) atomicAdd(&pk[(qi*32 + qt*16 + l15)*12 + k], v);
            }
    }
    __syncthreads();
    {
        float* dst = pkg + ((chunk*3 + dj)*B_ + b)*1152;
        for (int i = tid; i < 1152; i += 256) dst[i] = pk[i];
    }
}

// ---------------------------------------------------------------------------
// Final: merge chunk partials, log-mask-sum over q, dense dot. grid = B blocks.
// ---------------------------------------------------------------------------
__global__ void final_kernel(const float* __restrict__ pkg,
                             const int* __restrict__ qtok,
                             const float* __restrict__ dw,
                             float* __restrict__ out) {
    __shared__ float feats[99];
    __shared__ float qmsk[32];
    const int b = blockIdx.x, tid = threadIdx.x;
    if (tid < 32) qmsk[tid] = (tid < Qn && qtok[b*Qn + tid] > 0) ? 1.f : 0.f;
    __syncthreads();
    if (tid < 99) {
        int combo = tid / 11, k = tid - combo*11;
        int qi = combo / 3, dj = combo - qi*3;
        const float* p0 = pkg + ((0*3 + dj)*B_ + b)*1152 + qi*32*12 + k;
        const float* p1 = pkg + ((1*3 + dj)*B_ + b)*1152 + qi*32*12 + k;
        float s = 0.f;
        for (int q = 0; q < Qn; ++q) {
            float v = p0[q*12] + p1[q*12];
            s += qmsk[q] * 0.01f * logf(fmaxf(v, 1e-10f));
        }
        feats[tid] = s;
    }
    __syncthreads();
    if (tid == 0) {
        float s = 0.f;
        for (int f = 0; f < 99; ++f) s += feats[f] * dw[f];
        out[b] = s;
    }
}

extern "C" void kernel_launch(void* const* d_in, const int* in_sizes, int n_in,
                              void* d_out, int out_size, void* d_ws, size_t ws_size,
                              hipStream_t stream) {
    const int*   qtok = (const int*)d_in[0];
    const int*   dtok = (const int*)d_in[1];
    const float* emb  = (const float*)d_in[2];
    const float* w1   = (const float*)d_in[3];
    const float* w2   = (const float*)d_in[4];
    const float* w3   = (const float*)d_in[5];
    const float* b1   = (const float*)d_in[6];
    const float* b2   = (const float*)d_in[7];
    const float* b3   = (const float*)d_in[8];
    const float* dw   = (const float*)d_in[9];
    float* out = (float*)d_out;

    char* w = (char*)d_ws;
    u16*   Wt    = (u16*)w;                      // 491,520 B
    u16*   qg    = (u16*)(w + 491520);           // 3*128*32*128*2  = 3,145,728
    u16*   dgm   = (u16*)(w + 3637248);          // 3*128*208*128*2 = 20,447,232
    float* invq_ = (float*)(w + 24084480);       // 49,152
    float* invd_ = (float*)(w + 24133632);       // 319,488
    float* pkg   = (float*)(w + 24453120);       // 3,538,944 -> total 27,992,064

    prep_w_kernel<<<960, 256, 0, stream>>>(w1, w2, w3, Wt);

    const int conv_lds = 133120;
    hipFuncSetAttribute(reinterpret_cast<const void*>(conv_kernel),
                        hipFuncAttributeMaxDynamicSharedMemorySize, conv_lds);
    conv_kernel<<<dim3(2, B_), 256, conv_lds, stream>>>(
        qtok, dtok, emb, Wt, b1, b2, b3, qg, dgm, invq_, invd_);

    pool_kernel<<<dim3(6, B_), 256, 0, stream>>>(qg, dgm, invq_, invd_, qtok, dtok, pkg);

    final_kernel<<<B_, 128, 0, stream>>>(pkg, qtok, dw, out);
}